// Round 1
// baseline (116.673 us; speedup 1.0000x reference)
//
#include <hip/hip_runtime.h>

// Problem constants (fixed by setup_inputs: N=8192, D=8, fp32).
constexpr int N = 8192;
constexpr int D = 8;
constexpr int BLK = 256;          // i-rows per block (1 thread = 1 row)
constexpr int JTILE = 512;        // j-rows staged in LDS per block
constexpr int JCH = N / JTILE;    // 16 j-chunks -> grid.y

// counts[m*N + i] = #{ j : M[i,d] > M[j,d] for all d }, M = X (m=0) / X_hat (m=1)
__global__ __launch_bounds__(BLK) void dom_count_kernel(
    const float* __restrict__ X, const float* __restrict__ Xh,
    int* __restrict__ counts) {
  const float* M = (blockIdx.z == 0) ? X : Xh;
  int* cnt_out = counts + blockIdx.z * N;

  __shared__ float4 tile[JTILE * 2];   // 512 rows * 32 B = 16 KB

  const int tid = threadIdx.x;
  const int i = blockIdx.x * BLK + tid;

  // my row (8 floats, 32B-aligned)
  const float4* Mi = reinterpret_cast<const float4*>(M + (size_t)i * D);
  const float4 r0 = Mi[0];
  const float4 r1 = Mi[1];

  // stage j-tile cooperatively (coalesced float4 loads)
  const int j0 = blockIdx.y * JTILE;
  const float4* src = reinterpret_cast<const float4*>(M + (size_t)j0 * D);
  for (int k = tid; k < JTILE * 2; k += BLK) tile[k] = src[k];
  __syncthreads();

  int cnt = 0;
#pragma unroll 4
  for (int j = 0; j < JTILE; ++j) {
    // same-address broadcast reads -> conflict-free
    const float4 a = tile[2 * j];
    const float4 b = tile[2 * j + 1];
    const int ok = (r0.x > a.x) & (r0.y > a.y) & (r0.z > a.z) & (r0.w > a.w) &
                   (r1.x > b.x) & (r1.y > b.y) & (r1.z > b.z) & (r1.w > b.w);
    cnt += ok;
  }
  atomicAdd(&cnt_out[i], cnt);
}

// Sorting-free finisher:
//   sum_k |sort(a)_k - sort(b)_k|  ==  sum_t | #{a<=t} - #{b<=t} |
// Histogram the difference (+1 for X counts, -1 for X_hat counts), scan,
// sum |prefix|. Exact integer arithmetic; one 1024-thread block.
__global__ __launch_bounds__(1024) void finalize_kernel(
    const int* __restrict__ counts, float* __restrict__ out) {
  __shared__ int hist[N];      // 32 KB
  __shared__ int ssum[1024];   // 4 KB
  __shared__ int total;

  const int tid = threadIdx.x;
  for (int k = tid; k < N; k += 1024) hist[k] = 0;
  if (tid == 0) total = 0;
  __syncthreads();

  for (int k = tid; k < N; k += 1024) {
    atomicAdd(&hist[counts[k]], 1);
    atomicAdd(&hist[counts[N + k]], -1);
  }
  __syncthreads();

  // each thread owns 8 contiguous bins
  int local[8];
  int s = 0;
#pragma unroll
  for (int q = 0; q < 8; ++q) {
    local[q] = hist[tid * 8 + q];
    s += local[q];
  }

  // Hillis-Steele inclusive scan of chunk sums across 1024 threads
  ssum[tid] = s;
  __syncthreads();
  for (int off = 1; off < 1024; off <<= 1) {
    const int v = (tid >= off) ? ssum[tid - off] : 0;
    __syncthreads();
    ssum[tid] += v;
    __syncthreads();
  }

  int run = ssum[tid] - s;  // exclusive prefix of my chunk
  int acc = 0;
#pragma unroll
  for (int q = 0; q < 8; ++q) {
    run += local[q];
    acc += (run < 0) ? -run : run;
  }
  atomicAdd(&total, acc);
  __syncthreads();

  if (tid == 0) {
    // result = total / (N-1) / N
    out[0] = (float)((double)total / ((double)(N - 1) * (double)N));
  }
}

extern "C" void kernel_launch(void* const* d_in, const int* in_sizes, int n_in,
                              void* d_out, int out_size, void* d_ws, size_t ws_size,
                              hipStream_t stream) {
  const float* X = (const float*)d_in[0];
  const float* Xh = (const float*)d_in[1];
  float* out = (float*)d_out;
  int* counts = (int*)d_ws;  // 2*N ints = 64 KB scratch

  hipMemsetAsync(counts, 0, 2 * N * sizeof(int), stream);

  dim3 grid(N / BLK, JCH, 2);
  dom_count_kernel<<<grid, BLK, 0, stream>>>(X, Xh, counts);
  finalize_kernel<<<1, 1024, 0, stream>>>(counts, out);
}

// Round 2
// 110.896 us; speedup vs baseline: 1.0521x; 1.0521x over previous
//
#include <hip/hip_runtime.h>

// Problem constants (fixed by setup_inputs: N=8192, D=8, fp32).
constexpr int N = 8192;
constexpr int BLK = 256;            // threads per block
constexpr int IPT = 4;              // i-rows per thread (amortize LDS broadcast)
constexpr int ITILE = BLK * IPT;    // 1024 i-rows per block
constexpr int JTILE = 256;          // j-rows staged in LDS per block
constexpr int JCH = N / JTILE;      // 32 j-chunks -> grid.y

// counts[m*N + i] = #{ j : M[i,d] > M[j,d] for all d }, M = X (m=0) / X_hat (m=1)
// Dominance test via min-of-differences: min_d(Mi_d - Mj_d) > 0.
// This keeps the 8-way AND in the VALU (v_sub/v_min3) instead of 7 s_and_b64
// per j-step on the single per-CU scalar unit (the R1 bottleneck).
__global__ __launch_bounds__(BLK) void dom_count_kernel(
    const float* __restrict__ X, const float* __restrict__ Xh,
    int* __restrict__ counts) {
  const float* M = (blockIdx.z == 0) ? X : Xh;
  int* cnt_out = counts + blockIdx.z * N;

  __shared__ float4 tile[JTILE * 2];   // 256 rows * 32 B = 8 KB

  const int tid = threadIdx.x;
  const int ibase = blockIdx.x * ITILE + tid;   // rows ibase + p*BLK

  // stage j-tile cooperatively (coalesced float4 loads)
  const int j0 = blockIdx.y * JTILE;
  const float4* src = reinterpret_cast<const float4*>(M + (size_t)j0 * 8);
  for (int k = tid; k < JTILE * 2; k += BLK) tile[k] = src[k];

  // my IPT i-rows (coalesced: consecutive lanes -> consecutive rows)
  float4 r0[IPT], r1[IPT];
#pragma unroll
  for (int p = 0; p < IPT; ++p) {
    const float4* Mi = reinterpret_cast<const float4*>(M + (size_t)(ibase + p * BLK) * 8);
    r0[p] = Mi[0];
    r1[p] = Mi[1];
  }
  __syncthreads();

  int cnt[IPT] = {};
#pragma unroll 2
  for (int j = 0; j < JTILE; ++j) {
    // same-address broadcast reads -> conflict-free
    const float4 a = tile[2 * j];
    const float4 b = tile[2 * j + 1];
#pragma unroll
    for (int p = 0; p < IPT; ++p) {
      const float m0 = fminf(fminf(r0[p].x - a.x, r0[p].y - a.y),
                             fminf(r0[p].z - a.z, r0[p].w - a.w));
      const float m1 = fminf(fminf(r1[p].x - b.x, r1[p].y - b.y),
                             fminf(r1[p].z - b.z, r1[p].w - b.w));
      cnt[p] += (fminf(m0, m1) > 0.0f) ? 1 : 0;
    }
  }
#pragma unroll
  for (int p = 0; p < IPT; ++p) atomicAdd(&cnt_out[ibase + p * BLK], cnt[p]);
}

// Sorting-free finisher:
//   sum_k |sort(a)_k - sort(b)_k|  ==  sum_t | #{a<=t} - #{b<=t} |
// Histogram the difference (+1 for X counts, -1 for X_hat counts), scan,
// sum |prefix|. Exact integer arithmetic; one 1024-thread block.
// R2: wave-level shfl scans -> 4 barriers instead of 21.
__global__ __launch_bounds__(1024) void finalize_kernel(
    const int* __restrict__ counts, float* __restrict__ out) {
  __shared__ int hist[N];      // 32 KB
  __shared__ int wsum[16];     // per-wave chunk sums
  __shared__ int wexc[16];     // exclusive prefix per wave
  __shared__ int wabs[16];     // per-wave |prefix| partial sums

  const int tid = threadIdx.x;
  const int lane = tid & 63;
  const int wid = tid >> 6;

  for (int k = tid; k < N; k += 1024) hist[k] = 0;
  __syncthreads();

  for (int k = tid; k < N; k += 1024) {
    atomicAdd(&hist[counts[k]], 1);
    atomicAdd(&hist[counts[N + k]], -1);
  }
  __syncthreads();

  // each thread owns 8 contiguous bins
  int local[8];
  int s = 0;
#pragma unroll
  for (int q = 0; q < 8; ++q) {
    local[q] = hist[tid * 8 + q];
    s += local[q];
  }

  // wave-inclusive scan of per-thread sums (no barriers)
  int incl = s;
#pragma unroll
  for (int off = 1; off < 64; off <<= 1) {
    const int v = __shfl_up(incl, off);
    if (lane >= off) incl += v;
  }
  if (lane == 63) wsum[wid] = incl;
  __syncthreads();

  if (tid == 0) {
    int acc = 0;
#pragma unroll
    for (int w = 0; w < 16; ++w) { wexc[w] = acc; acc += wsum[w]; }
  }
  __syncthreads();

  int run = wexc[wid] + (incl - s);  // exclusive prefix of my 8-bin chunk
  int acc = 0;
#pragma unroll
  for (int q = 0; q < 8; ++q) {
    run += local[q];
    acc += (run < 0) ? -run : run;
  }

  // block reduction of acc: wave shfl + tiny LDS pass
#pragma unroll
  for (int off = 32; off > 0; off >>= 1) acc += __shfl_down(acc, off);
  if (lane == 0) wabs[wid] = acc;
  __syncthreads();

  if (tid == 0) {
    int total = 0;
#pragma unroll
    for (int w = 0; w < 16; ++w) total += wabs[w];
    // result = total / (N-1) / N
    out[0] = (float)((double)total / ((double)(N - 1) * (double)N));
  }
}

extern "C" void kernel_launch(void* const* d_in, const int* in_sizes, int n_in,
                              void* d_out, int out_size, void* d_ws, size_t ws_size,
                              hipStream_t stream) {
  const float* X = (const float*)d_in[0];
  const float* Xh = (const float*)d_in[1];
  float* out = (float*)d_out;
  int* counts = (int*)d_ws;  // 2*N ints = 64 KB scratch

  hipMemsetAsync(counts, 0, 2 * N * sizeof(int), stream);

  dim3 grid(N / ITILE, JCH, 2);
  dom_count_kernel<<<grid, BLK, 0, stream>>>(X, Xh, counts);
  finalize_kernel<<<1, 1024, 0, stream>>>(counts, out);
}

// Round 3
// 104.686 us; speedup vs baseline: 1.1145x; 1.0593x over previous
//
#include <hip/hip_runtime.h>

// Problem constants (fixed by setup_inputs: N=8192, D=8, fp32).
constexpr int N = 8192;
constexpr int BLK = 256;            // threads per block
constexpr int IPT = 4;              // i-rows per thread
constexpr int ITILE = BLK * IPT;    // 1024 i-rows per block
constexpr int JTILE = 256;          // j-rows staged in LDS per block
constexpr int JCH = N / JTILE;      // 32 j-chunks -> grid.y

// Force single-instruction 3-input min (clang won't fuse a balanced fminf
// tree, and fminf lowering cost ~2x what we expect per R2 counters).
__device__ __forceinline__ float min3f(float a, float b, float c) {
  float r;
  asm("v_min3_f32 %0, %1, %2, %3" : "=v"(r) : "v"(a), "v"(b), "v"(c));
  return r;
}
__device__ __forceinline__ float min2f(float a, float b) {
  float r;
  asm("v_min_f32 %0, %1, %2" : "=v"(r) : "v"(a), "v"(b));
  return r;
}

// counts[m*N + i] = #{ j : M[i,d] > M[j,d] for all d }
// Strict dominance via min-of-differences: min_d(Mi_d - Mj_d) > 0.
// Exact: ties (diff==+0) and self (all diffs 0) give min <= 0 -> rejected.
__global__ __launch_bounds__(BLK) void dom_count_kernel(
    const float* __restrict__ X, const float* __restrict__ Xh,
    int* __restrict__ counts) {
  const float* M = (blockIdx.z == 0) ? X : Xh;
  int* cnt_out = counts + blockIdx.z * N;

  __shared__ float4 tile[JTILE * 2];   // 256 rows * 32 B = 8 KB

  const int tid = threadIdx.x;
  const int ibase = blockIdx.x * ITILE + tid;   // rows ibase + p*BLK

  // stage j-tile cooperatively (coalesced float4 loads)
  const int j0 = blockIdx.y * JTILE;
  const float4* src = reinterpret_cast<const float4*>(M + (size_t)j0 * 8);
  for (int k = tid; k < JTILE * 2; k += BLK) tile[k] = src[k];

  // my IPT i-rows (coalesced: consecutive lanes -> consecutive rows)
  float4 r0[IPT], r1[IPT];
#pragma unroll
  for (int p = 0; p < IPT; ++p) {
    const float4* Mi = reinterpret_cast<const float4*>(M + (size_t)(ibase + p * BLK) * 8);
    r0[p] = Mi[0];
    r1[p] = Mi[1];
  }
  __syncthreads();

  int cnt[IPT] = {};
#pragma unroll 2
  for (int j = 0; j < JTILE; ++j) {
    // same-address broadcast reads -> conflict-free
    const float4 a = tile[2 * j];
    const float4 b = tile[2 * j + 1];
#pragma unroll
    for (int p = 0; p < IPT; ++p) {
      const float t0 = min3f(r0[p].x - a.x, r0[p].y - a.y, r0[p].z - a.z);
      const float t1 = min3f(r0[p].w - a.w, r1[p].x - b.x, r1[p].y - b.y);
      const float t2 = min2f(r1[p].z - b.z, r1[p].w - b.w);
      cnt[p] += (min3f(t0, t1, t2) > 0.0f) ? 1 : 0;
    }
  }
#pragma unroll
  for (int p = 0; p < IPT; ++p) atomicAdd(&cnt_out[ibase + p * BLK], cnt[p]);
}

// --- Finalize, stage 1: privatized histograms -------------------------------
// sum_k |sort(a)_k - sort(b)_k| == sum_t |#{a<=t} - #{b<=t}|.
// Histogram the difference (+1 for X counts, -1 for Xh counts).
// Counts concentrate near 0 (P(dom) ~ 2^-8), so a single-block LDS histogram
// serializes on hot bins (the hidden ~45us in R1/R2). 16 blocks privatize the
// contention and run on 16 CUs; merge only nonzero bins into global hist.
constexpr int HB = 16;  // histogram blocks
__global__ __launch_bounds__(1024) void hist_partial_kernel(
    const int* __restrict__ counts, int* __restrict__ ghist) {
  __shared__ int lhist[N];  // 32 KB
  const int tid = threadIdx.x;
  for (int q = tid; q < N; q += 1024) lhist[q] = 0;
  __syncthreads();

  const int k = blockIdx.x * (2 * N / HB) + tid;  // 1024 values per block
  const int v = counts[k];
  atomicAdd(&lhist[v], (k < N) ? 1 : -1);
  __syncthreads();

#pragma unroll
  for (int q = 0; q < N / 1024; ++q) {
    const int bin = tid * (N / 1024) + q;
    const int h = lhist[bin];
    if (h != 0) atomicAdd(&ghist[bin], h);
  }
}

// --- Finalize, stage 2: scan + abs-sum (one small block) --------------------
__global__ __launch_bounds__(1024) void finalize_kernel(
    const int* __restrict__ ghist, float* __restrict__ out) {
  __shared__ int wsum[16];
  __shared__ int wexc[16];
  __shared__ int wabs[16];

  const int tid = threadIdx.x;
  const int lane = tid & 63;
  const int wid = tid >> 6;

  // each thread owns 8 contiguous bins
  int local[8];
  int s = 0;
#pragma unroll
  for (int q = 0; q < 8; ++q) {
    local[q] = ghist[tid * 8 + q];
    s += local[q];
  }

  // wave-inclusive scan of per-thread sums
  int incl = s;
#pragma unroll
  for (int off = 1; off < 64; off <<= 1) {
    const int v = __shfl_up(incl, off);
    if (lane >= off) incl += v;
  }
  if (lane == 63) wsum[wid] = incl;
  __syncthreads();

  if (tid == 0) {
    int acc = 0;
#pragma unroll
    for (int w = 0; w < 16; ++w) { wexc[w] = acc; acc += wsum[w]; }
  }
  __syncthreads();

  int run = wexc[wid] + (incl - s);  // exclusive prefix of my 8-bin chunk
  int acc = 0;
#pragma unroll
  for (int q = 0; q < 8; ++q) {
    run += local[q];
    acc += (run < 0) ? -run : run;
  }

#pragma unroll
  for (int off = 32; off > 0; off >>= 1) acc += __shfl_down(acc, off);
  if (lane == 0) wabs[wid] = acc;
  __syncthreads();

  if (tid == 0) {
    int total = 0;
#pragma unroll
    for (int w = 0; w < 16; ++w) total += wabs[w];
    // result = total / (N-1) / N
    out[0] = (float)((double)total / ((double)(N - 1) * (double)N));
  }
}

extern "C" void kernel_launch(void* const* d_in, const int* in_sizes, int n_in,
                              void* d_out, int out_size, void* d_ws, size_t ws_size,
                              hipStream_t stream) {
  const float* X = (const float*)d_in[0];
  const float* Xh = (const float*)d_in[1];
  float* out = (float*)d_out;
  int* counts = (int*)d_ws;        // 2*N ints = 64 KB
  int* ghist = counts + 2 * N;     // N ints = 32 KB

  hipMemsetAsync(counts, 0, (2 * N + N) * sizeof(int), stream);

  dim3 grid(N / ITILE, JCH, 2);
  dom_count_kernel<<<grid, BLK, 0, stream>>>(X, Xh, counts);
  hist_partial_kernel<<<HB, 1024, 0, stream>>>(counts, ghist);
  finalize_kernel<<<1, 1024, 0, stream>>>(ghist, out);
}